// Round 7
// baseline (287.588 us; speedup 1.0000x reference)
//
#include <hip/hip_runtime.h>
#include <hip/hip_fp16.h>

// GCN: 3x (GEMM(+BN fold) -> CSR aggregate x2 feature-halves -> BN-stats),
// then segment mean-pool + linear head + softmax.
// Sizes fixed: N=65536 nodes, E=1048576 edges, F=H=64, 64 graphs, 16 classes.
//
// CSR build: LDS-local binning -> 1-block bucket scan -> place (LDS count +
// local scan + in-window scatter).
// r5: fp16 activations. r6: quad-gather (neutral-ish -> memory-side bound).
// r7 experiment: y split into two 4MB feature-half arrays so each k_agg's
// gather working set fits one XCD's 4MB L2 (tests L2-capacity hypothesis;
// byte and line demand unchanged).

#define NBKT 512      // bucket = dst >> 7 (128 nodes per bucket)
#define CAP  4096     // slots per bucket (avg fill 2048)
#define BSTRIDE 16    // bcur padded: one counter per 64B line

__device__ inline unsigned pack2h(float a, float b) {
    __half ha = __float2half_rn(a), hb = __float2half_rn(b);
    unsigned short ua = *(unsigned short*)&ha, ub = *(unsigned short*)&hb;
    return (unsigned)ua | ((unsigned)ub << 16);
}

__device__ inline float4 cvt4(uint2 u) {
    __half2 h0 = *(__half2*)&u.x, h1 = *(__half2*)&u.y;
    float2 f0 = __half22float2(h0), f1 = __half22float2(h1);
    return {f0.x, f0.y, f1.x, f1.y};
}

__global__ void k_binit(int* __restrict__ bcur) {
    int t = blockIdx.x * 256 + threadIdx.x;
    if (t < NBKT) bcur[t * BSTRIDE] = t * CAP;
}

// partition edges into NBKT dst-buckets; entries packed (src<<7)|(dst&127)
__global__ void k_bin(const int* __restrict__ ei, int E, int* __restrict__ bcur,
                      int* __restrict__ buck) {
    __shared__ int sd[4096];
    __shared__ unsigned short bk[4096];
    __shared__ int cnt[NBKT], off[NBKT];
    int t = threadIdx.x;
    int base = blockIdx.x * 4096;
    for (int i = t; i < NBKT; i += 256) cnt[i] = 0;
    __syncthreads();
#pragma unroll
    for (int k = 0; k < 16; ++k) {
        int i = k * 256 + t;
        int e = base + i;
        int s = ei[e], d = ei[E + e];
        sd[i] = (s << 7) | (d & 127);
        int b = d >> 7;
        bk[i] = (unsigned short)b;
        atomicAdd(&cnt[b], 1);
    }
    __syncthreads();
    for (int b = t; b < NBKT; b += 256) {
        int c = cnt[b];
        off[b] = c ? atomicAdd(&bcur[b * BSTRIDE], c) : 0;
    }
    __syncthreads();
#pragma unroll
    for (int k = 0; k < 16; ++k) {
        int i = k * 256 + t;
        int b = bk[i];
        int p = atomicAdd(&off[b], 1);
        buck[p] = sd[i];
    }
}

// exclusive scan over bucket counts; also zeros psum/pcnt and sets rowptr[N]
__global__ void k_scanB(const int* __restrict__ bcur, int* __restrict__ bbase,
                        int* __restrict__ rowptr, float* __restrict__ psum,
                        float* __restrict__ pcnt, int N, int E) {
    __shared__ int s[NBKT];
    int t = threadIdx.x;
    int v = bcur[t * BSTRIDE] - t * CAP;
    s[t] = v;
    __syncthreads();
    for (int o = 1; o < NBKT; o <<= 1) {
        int x = (t >= o) ? s[t - o] : 0;
        __syncthreads();
        s[t] += x;
        __syncthreads();
    }
    bbase[t] = s[t] - v;
    for (int i = t; i < 4096; i += NBKT) psum[i] = 0.0f;
    if (t < 64) pcnt[t] = 0.0f;
    if (t == 0) rowptr[N] = E;
}

// per bucket: count node degrees in LDS, local 128-scan -> rowptr/dinv, scatter csr
__global__ void k_place(const int* __restrict__ bcur, const int* __restrict__ buck,
                        const int* __restrict__ bbase, int* __restrict__ rowptr,
                        float* __restrict__ dinv, int* __restrict__ csr) {
    __shared__ int dc[128], sc[128], cur[128];
    int b = blockIdx.x, t = threadIdx.x;
    if (t < 128) dc[t] = 0;
    __syncthreads();
    int beg = b * CAP, end = bcur[b * BSTRIDE];
    for (int i = beg + t; i < end; i += 256) atomicAdd(&dc[buck[i] & 127], 1);
    __syncthreads();
    int v = (t < 128) ? dc[t] : 0;
    if (t < 128) sc[t] = v;
    __syncthreads();
    for (int o = 1; o < 128; o <<= 1) {
        int x = 0;
        if (t < 128 && t >= o) x = sc[t - o];
        __syncthreads();
        if (t < 128) sc[t] += x;
        __syncthreads();
    }
    if (t < 128) {
        int r = bbase[b] + sc[t] - v;   // exclusive
        rowptr[b * 128 + t] = r;
        cur[t] = r;
        dinv[b * 128 + t] = rsqrtf((float)(v + 1));  // +1 self loop
    }
    __syncthreads();
    for (int i = beg + t; i < end; i += 256) {
        int e = buck[i];
        int p = atomicAdd(&cur[e & 127], 1);
        csr[p] = e >> 7;
    }
}

// y{0,1}[n][j] = fp16( dinv[n] * ( sum_f hnorm[n][f]*W[f][j] + brow[j] ) )
// BN fold in-block: Ws = rstd[f]*W, brow[j] = -sum_f mean[f]*Ws[f][j].
// block 256 threads, 64 rows/block; thread = 4x4 output tile.
// Output split by feature half: y0 = cols 0..31, y1 = cols 32..63 (4MB each).
template <int HIN>
__global__ void k_gemm(const void* __restrict__ hv, const float* __restrict__ W,
                       const float* __restrict__ mean, const float* __restrict__ rstd,
                       int has_stats, const float* __restrict__ dinv,
                       __half* __restrict__ y0, __half* __restrict__ y1) {
    __shared__ float Ws[4096];        // [f][c] 64x64, scaled by rstd[f]
    __shared__ float hs[64 * 65];     // [row][f], stride 65
    __shared__ float sm[64], sr[64], bs[64];
    int t = threadIdx.x;
    int rowBase = blockIdx.x * 64;
    if (t < 64) {
        sm[t] = has_stats ? mean[t] : 0.0f;
        sr[t] = has_stats ? rstd[t] : 1.0f;
    }
    __syncthreads();
#pragma unroll
    for (int k = 0; k < 4; ++k) {
        int i = t + k * 256;              // float4 index; row f = i>>4
        float4 wv = ((const float4*)W)[i];
        float s = sr[i >> 4];
        wv.x *= s; wv.y *= s; wv.z *= s; wv.w *= s;
        ((float4*)Ws)[i] = wv;
    }
    if (HIN) {
        const uint4* src = (const uint4*)((const __half*)hv + (size_t)rowBase * 64);
#pragma unroll
        for (int k = 0; k < 2; ++k) {
            int i = t + k * 256;          // 0..511 uint4s; each = 8 halves
            int row = i >> 3, c8 = i & 7;
            uint4 u = src[i];
            const __half2* hp = (const __half2*)&u;
            float* dst = &hs[row * 65 + c8 * 8];
#pragma unroll
            for (int j = 0; j < 4; ++j) {
                dst[2 * j + 0] = __low2float(hp[j]);
                dst[2 * j + 1] = __high2float(hp[j]);
            }
        }
    } else {
        const float4* src = (const float4*)((const float*)hv + (size_t)rowBase * 64);
#pragma unroll
        for (int k = 0; k < 4; ++k) {
            int i = t + k * 256;
            int row = i >> 4, c4 = i & 15;
            float4 v = src[i];
            float* dst = &hs[row * 65 + c4 * 4];
            dst[0] = v.x; dst[1] = v.y; dst[2] = v.z; dst[3] = v.w;
        }
    }
    __syncthreads();
    if (t < 64) {
        float acc = 0.0f;
        for (int f = 0; f < 64; ++f) acc += sm[f] * Ws[f * 64 + t];
        bs[t] = -acc;
    }
    __syncthreads();
    int rg = t >> 4;   // 0..15
    int cg = t & 15;   // 0..15
    float4 a0, a1, a2, a3;
    {
        float bx = bs[cg * 4 + 0], by = bs[cg * 4 + 1];
        float bz = bs[cg * 4 + 2], bw = bs[cg * 4 + 3];
        a0 = {bx, by, bz, bw}; a1 = a0; a2 = a0; a3 = a0;
    }
    const float* h0 = &hs[(rg * 4 + 0) * 65];
    const float* h1 = &hs[(rg * 4 + 1) * 65];
    const float* h2 = &hs[(rg * 4 + 2) * 65];
    const float* h3 = &hs[(rg * 4 + 3) * 65];
#pragma unroll 4
    for (int f = 0; f < 64; ++f) {
        float4 wv = ((float4*)Ws)[f * 16 + cg];
        float v0 = h0[f], v1 = h1[f], v2 = h2[f], v3 = h3[f];
        a0.x += v0 * wv.x; a0.y += v0 * wv.y; a0.z += v0 * wv.z; a0.w += v0 * wv.w;
        a1.x += v1 * wv.x; a1.y += v1 * wv.y; a1.z += v1 * wv.z; a1.w += v1 * wv.w;
        a2.x += v2 * wv.x; a2.y += v2 * wv.y; a2.z += v2 * wv.z; a2.w += v2 * wv.w;
        a3.x += v3 * wv.x; a3.y += v3 * wv.y; a3.z += v3 * wv.z; a3.w += v3 * wv.w;
    }
    float d0 = dinv[rowBase + rg * 4 + 0];
    float d1 = dinv[rowBase + rg * 4 + 1];
    float d2 = dinv[rowBase + rg * 4 + 2];
    float d3 = dinv[rowBase + rg * 4 + 3];
    uint2* dsty = (cg < 8) ? (uint2*)y0 : (uint2*)y1;
    int lc = cg & 7;
    size_t ob = (size_t)(rowBase + rg * 4) * 8 + lc;
    dsty[ob + 0]  = {pack2h(a0.x * d0, a0.y * d0), pack2h(a0.z * d0, a0.w * d0)};
    dsty[ob + 8]  = {pack2h(a1.x * d1, a1.y * d1), pack2h(a1.z * d1, a1.w * d1)};
    dsty[ob + 16] = {pack2h(a2.x * d2, a2.y * d2), pack2h(a2.z * d2, a2.w * d2)};
    dsty[ob + 24] = {pack2h(a3.x * d3, a3.y * d3), pack2h(a3.z * d3, a3.w * d3)};
}

// Half-feature aggregate: out[n][HALF*32+:32] from yh (4MB, fits one XCD L2).
// Octet-gather: octet o (8 lanes) holds 8 features (uint2=4) per... lane l holds
// features l*4..l*4+3 of the half; octet o processes edges k+o.
template <int RELU, int HALF>
__global__ void k_agg(const __half* __restrict__ yh, const int* __restrict__ rowptr,
                      const int* __restrict__ csr, const float* __restrict__ dinv,
                      const float* __restrict__ bias, __half* __restrict__ hout,
                      float* __restrict__ partials, int N) {
    int t = threadIdx.x;
    int lane = t & 63;
    int wid = t >> 6;                       // 0..7
    int o = lane >> 3;                      // octet 0..7
    int l = lane & 7;                       // uint2 index within 64B row
    int gwave = blockIdx.x * 8 + wid;       // 0..16383
    float4 bv = ((const float4*)bias)[HALF * 8 + l];
    float4 ps = {0, 0, 0, 0}, pq = {0, 0, 0, 0};
    const uint2* y2 = (const uint2*)yh;     // row = 8 uint2 = 64B
    for (int n = gwave; n < N; n += 16384) {
        int beg = rowptr[n], end = rowptr[n + 1];
        int d = end - beg;
        const int* cp = csr + beg;
        float4 acc = {0, 0, 0, 0};
        int nfull = d >> 3;
        int i = 0;
        for (; i + 2 <= nfull; i += 2) {    // 16 edges per iter, 2 chains in flight
            int s0 = cp[8 * i + o];
            int s1 = cp[8 * i + 8 + o];
            uint2 u0 = y2[(size_t)s0 * 8 + l];
            uint2 u1 = y2[(size_t)s1 * 8 + l];
            float4 v0 = cvt4(u0), v1 = cvt4(u1);
            acc.x += v0.x + v1.x;
            acc.y += v0.y + v1.y;
            acc.z += v0.z + v1.z;
            acc.w += v0.w + v1.w;
        }
        if (i < nfull) {
            int s0 = cp[8 * i + o];
            uint2 u0 = y2[(size_t)s0 * 8 + l];
            float4 v0 = cvt4(u0);
            acc.x += v0.x; acc.y += v0.y; acc.z += v0.z; acc.w += v0.w;
        }
        int r = d & 7;
        if (r) {
            int e = min(8 * nfull + o, d - 1);
            uint2 u0 = y2[(size_t)cp[e] * 8 + l];
            float4 v0 = cvt4(u0);
            if (o < r) {
                acc.x += v0.x; acc.y += v0.y; acc.z += v0.z; acc.w += v0.w;
            }
        }
        // combine octets
#pragma unroll
        for (int m = 8; m <= 32; m <<= 1) {
            acc.x += __shfl_xor(acc.x, m);
            acc.y += __shfl_xor(acc.y, m);
            acc.z += __shfl_xor(acc.z, m);
            acc.w += __shfl_xor(acc.w, m);
        }
        float4 vs = cvt4(y2[(size_t)n * 8 + l]);   // self term
        float dv = dinv[n];
        float4 val;
        val.x = (acc.x + vs.x) * dv + bv.x;
        val.y = (acc.y + vs.y) * dv + bv.y;
        val.z = (acc.z + vs.z) * dv + bv.z;
        val.w = (acc.w + vs.w) * dv + bv.w;
        if (RELU) {
            val.x = fmaxf(val.x, 0.0f); val.y = fmaxf(val.y, 0.0f);
            val.z = fmaxf(val.z, 0.0f); val.w = fmaxf(val.w, 0.0f);
        }
        if (o == 0) {
            uint2 o2;
            o2.x = pack2h(val.x, val.y);
            o2.y = pack2h(val.z, val.w);
            ((uint2*)hout)[(size_t)n * 16 + HALF * 8 + l] = o2;
        }
        ps.x += val.x; ps.y += val.y; ps.z += val.z; ps.w += val.w;
        pq.x += val.x * val.x; pq.y += val.y * val.y;
        pq.z += val.z * val.z; pq.w += val.w * val.w;
    }
    __shared__ float S[8][32], Q[8][32];
    if (o == 0) {
        ((float4*)S[wid])[l] = ps;
        ((float4*)Q[wid])[l] = pq;
    }
    __syncthreads();
    if (t < 32) {
        float s = 0.0f, qq = 0.0f;
#pragma unroll
        for (int w = 0; w < 8; ++w) {
            s += S[w][t];
            qq += Q[w][t];
        }
        partials[(size_t)blockIdx.x * 128 + HALF * 32 + t] = s;
        partials[(size_t)blockIdx.x * 128 + 64 + HALF * 32 + t] = qq;
    }
}

// one block per feature: reduce partials -> mean, rstd
__global__ void k_stats(const float* __restrict__ partials, int nblk,
                        float* __restrict__ mean, float* __restrict__ rstd, float invN) {
    __shared__ float sh[256];
    int f = blockIdx.x, t = threadIdx.x;
    float s = 0.0f, q = 0.0f;
    for (int b = t; b < nblk; b += 256) {
        s += partials[(size_t)b * 128 + f];
        q += partials[(size_t)b * 128 + 64 + f];
    }
    sh[t] = s;
    __syncthreads();
    for (int o = 128; o > 0; o >>= 1) {
        if (t < o) sh[t] += sh[t + o];
        __syncthreads();
    }
    float S = sh[0];
    __syncthreads();
    sh[t] = q;
    __syncthreads();
    for (int o = 128; o > 0; o >>= 1) {
        if (t < o) sh[t] += sh[t + o];
        __syncthreads();
    }
    if (t == 0) {
        float Qs = sh[0];
        float m = S * invN;
        float var = Qs * invN - m * m;
        mean[f] = m;
        rstd[f] = rsqrtf(var + 1e-5f);
    }
}

// mean pool with on-the-fly BN of final layer; batch is sorted -> per-run register accum
__global__ void k_pool(const __half* __restrict__ h, const int* __restrict__ batch,
                       const float* __restrict__ mean, const float* __restrict__ rstd,
                       float* __restrict__ psum, float* __restrict__ pcnt) {
    int lane = threadIdx.x;
    int base = blockIdx.x * 64;
    float m = mean[lane], r = rstd[lane];
    int cur = batch[base];
    float acc = 0.0f;
    int runlen = 0;
    for (int i = 0; i < 64; ++i) {
        int n = base + i;
        int g = batch[n];
        if (g != cur) {
            atomicAdd(&psum[cur * 64 + lane], acc);
            if (lane == 0) atomicAdd(&pcnt[cur], (float)runlen);
            acc = 0.0f;
            runlen = 0;
            cur = g;
        }
        acc += (__half2float(h[(size_t)n * 64 + lane]) - m) * r;
        runlen++;
    }
    atomicAdd(&psum[cur * 64 + lane], acc);
    if (lane == 0) atomicAdd(&pcnt[cur], (float)runlen);
}

// logits = pooled @ clfW^T + clfb ; softmax over 16 classes. 1 block x 1024 threads.
__global__ void k_head(const float* __restrict__ psum, const float* __restrict__ pcnt,
                       const float* __restrict__ clfW, const float* __restrict__ clfb,
                       float* __restrict__ out) {
    __shared__ float ps[64 * 64];
    __shared__ float wl[16 * 64];
    __shared__ float ci[64];
    int t = threadIdx.x;
    ((float4*)ps)[t] = ((const float4*)psum)[t];
    if (t < 256) ((float4*)wl)[t] = ((const float4*)clfW)[t];
    if (t < 64) ci[t] = 1.0f / fmaxf(pcnt[t], 1.0f);
    __syncthreads();
    int g = t >> 4, c = t & 15;
    float acc = 0.0f;
#pragma unroll 8
    for (int f = 0; f < 64; ++f) acc += ps[g * 64 + f] * wl[c * 64 + f];
    acc = acc * ci[g] + clfb[c];
    float mx = acc;
    for (int o = 1; o < 16; o <<= 1) mx = fmaxf(mx, __shfl_xor(mx, o, 16));
    float e = __expf(acc - mx);
    float s = e;
    for (int o = 1; o < 16; o <<= 1) s += __shfl_xor(s, o, 16);
    out[t] = e / s;
}

extern "C" void kernel_launch(void* const* d_in, const int* in_sizes, int n_in,
                              void* d_out, int out_size, void* d_ws, size_t ws_size,
                              hipStream_t stream) {
    const float* x    = (const float*)d_in[0];
    const int*   ei   = (const int*)d_in[1];
    const int*   bat  = (const int*)d_in[2];
    const float* W0   = (const float*)d_in[3];
    const float* b0   = (const float*)d_in[4];
    const float* W1   = (const float*)d_in[5];
    const float* b1   = (const float*)d_in[6];
    const float* W2   = (const float*)d_in[7];
    const float* b2   = (const float*)d_in[8];
    const float* clfW = (const float*)d_in[9];
    const float* clfb = (const float*)d_in[10];
    float* out = (float*)d_out;

    const int N = in_sizes[0] / 64;   // 65536
    const int E = in_sizes[1] / 2;    // 1048576

    char* w = (char*)d_ws;
    size_t off = 0;
    auto take = [&](size_t bytes) -> void* {
        off = (off + 255) & ~(size_t)255;
        void* p = w + off;
        off += bytes;
        return p;
    };
    int*    rowptr   = (int*)take((size_t)(N + 1) * 4);
    int*    bcur     = (int*)take((size_t)NBKT * BSTRIDE * 4);
    int*    bbase    = (int*)take((size_t)NBKT * 4);
    float*  dinv     = (float*)take((size_t)N * 4);
    int*    csr      = (int*)take((size_t)E * 4);
    __half* y0       = (__half*)take((size_t)N * 32 * 2);
    __half* y1       = (__half*)take((size_t)N * 32 * 2);
    __half* hA       = (__half*)take((size_t)N * 64 * 2);
    __half* hB       = (__half*)take((size_t)N * 64 * 2);
    float*  partials = (float*)take((size_t)2048 * 128 * 4);
    float*  mean     = (float*)take(256);
    float*  rstd     = (float*)take(256);
    float*  psum     = (float*)take(64 * 64 * 4);
    float*  pcnt     = (float*)take(64 * 4);
    // buck (NBKT*CAP ints = 8MB) overlaid on hB (8MB fp16): buck dead after k_place,
    // hB first written in layer-1 k_agg.
    int* buck = (int*)hB;

    k_binit<<<(NBKT + 255) / 256, 256, 0, stream>>>(bcur);
    k_bin<<<E / 4096, 256, 0, stream>>>(ei, E, bcur, buck);
    k_scanB<<<1, NBKT, 0, stream>>>(bcur, bbase, rowptr, psum, pcnt, N, E);
    k_place<<<NBKT, 256, 0, stream>>>(bcur, buck, bbase, rowptr, dinv, csr);

    const float invN = 1.0f / (float)N;

    // layer 0 (input x fp32, no BN on input)
    k_gemm<0><<<N / 64, 256, 0, stream>>>(x, W0, mean, rstd, 0, dinv, y0, y1);
    k_agg<1, 0><<<2048, 512, 0, stream>>>(y0, rowptr, csr, dinv, b0, hA, partials, N);
    k_agg<1, 1><<<2048, 512, 0, stream>>>(y1, rowptr, csr, dinv, b0, hA, partials, N);
    k_stats<<<64, 256, 0, stream>>>(partials, 2048, mean, rstd, invN);

    // layer 1
    k_gemm<1><<<N / 64, 256, 0, stream>>>(hA, W1, mean, rstd, 1, dinv, y0, y1);
    k_agg<1, 0><<<2048, 512, 0, stream>>>(y0, rowptr, csr, dinv, b1, hB, partials, N);
    k_agg<1, 1><<<2048, 512, 0, stream>>>(y1, rowptr, csr, dinv, b1, hB, partials, N);
    k_stats<<<64, 256, 0, stream>>>(partials, 2048, mean, rstd, invN);

    // layer 2 (no relu)
    k_gemm<1><<<N / 64, 256, 0, stream>>>(hB, W2, mean, rstd, 1, dinv, y0, y1);
    k_agg<0, 0><<<2048, 512, 0, stream>>>(y0, rowptr, csr, dinv, b2, hA, partials, N);
    k_agg<0, 1><<<2048, 512, 0, stream>>>(y1, rowptr, csr, dinv, b2, hA, partials, N);
    k_stats<<<64, 256, 0, stream>>>(partials, 2048, mean, rstd, invN);

    // pool (applies final BN on the fly) + head
    k_pool<<<N / 64, 64, 0, stream>>>(hA, bat, mean, rstd, psum, pcnt);
    k_head<<<1, 1024, 0, stream>>>(psum, pcnt, clfW, clfb, out);
}

// Round 8
// 188.395 us; speedup vs baseline: 1.5265x; 1.5265x over previous
//
#include <hip/hip_runtime.h>
#include <hip/hip_fp16.h>

// GCN: 3x (GEMM(+BN fold) -> CSR aggregate -> BN-stats), then mean-pool + head.
// Sizes fixed: N=65536 nodes, E=1048576 edges, F=H=64, 64 graphs, 16 classes.
//
// CSR build: LDS-local binning -> 1-block bucket scan -> place.
// r5: fp16 activations. r6: quad-gather. r7: L2-capacity split REGRESSED (reverted).
// r8: k_agg redesign -- block stages its 64-node csr window in LDS (kills the
// per-node rowptr->csr global chain), octet-per-node gather with 4-deep unroll
// -> 32 row-loads in flight per wave (was 2). Latency-bound fix.

#define NBKT 512      // bucket = dst >> 7 (128 nodes per bucket)
#define CAP  4096     // slots per bucket (avg fill 2048)
#define BSTRIDE 16    // bcur padded: one counter per 64B line

__device__ inline unsigned pack2h(float a, float b) {
    __half ha = __float2half_rn(a), hb = __float2half_rn(b);
    unsigned short ua = *(unsigned short*)&ha, ub = *(unsigned short*)&hb;
    return (unsigned)ua | ((unsigned)ub << 16);
}

__device__ inline void acc8(float* a, uint4 u) {
    __half2* hp = (__half2*)&u;
#pragma unroll
    for (int i = 0; i < 4; ++i) {
        float2 f = __half22float2(hp[i]);
        a[2 * i] += f.x;
        a[2 * i + 1] += f.y;
    }
}

__global__ void k_binit(int* __restrict__ bcur) {
    int t = blockIdx.x * 256 + threadIdx.x;
    if (t < NBKT) bcur[t * BSTRIDE] = t * CAP;
}

// partition edges into NBKT dst-buckets; entries packed (src<<7)|(dst&127)
__global__ void k_bin(const int* __restrict__ ei, int E, int* __restrict__ bcur,
                      int* __restrict__ buck) {
    __shared__ int sd[4096];
    __shared__ unsigned short bk[4096];
    __shared__ int cnt[NBKT], off[NBKT];
    int t = threadIdx.x;
    int base = blockIdx.x * 4096;
    for (int i = t; i < NBKT; i += 256) cnt[i] = 0;
    __syncthreads();
#pragma unroll
    for (int k = 0; k < 16; ++k) {
        int i = k * 256 + t;
        int e = base + i;
        int s = ei[e], d = ei[E + e];
        sd[i] = (s << 7) | (d & 127);
        int b = d >> 7;
        bk[i] = (unsigned short)b;
        atomicAdd(&cnt[b], 1);
    }
    __syncthreads();
    for (int b = t; b < NBKT; b += 256) {
        int c = cnt[b];
        off[b] = c ? atomicAdd(&bcur[b * BSTRIDE], c) : 0;
    }
    __syncthreads();
#pragma unroll
    for (int k = 0; k < 16; ++k) {
        int i = k * 256 + t;
        int b = bk[i];
        int p = atomicAdd(&off[b], 1);
        buck[p] = sd[i];
    }
}

// exclusive scan over bucket counts; also zeros psum/pcnt and sets rowptr[N]
__global__ void k_scanB(const int* __restrict__ bcur, int* __restrict__ bbase,
                        int* __restrict__ rowptr, float* __restrict__ psum,
                        float* __restrict__ pcnt, int N, int E) {
    __shared__ int s[NBKT];
    int t = threadIdx.x;
    int v = bcur[t * BSTRIDE] - t * CAP;
    s[t] = v;
    __syncthreads();
    for (int o = 1; o < NBKT; o <<= 1) {
        int x = (t >= o) ? s[t - o] : 0;
        __syncthreads();
        s[t] += x;
        __syncthreads();
    }
    bbase[t] = s[t] - v;
    for (int i = t; i < 4096; i += NBKT) psum[i] = 0.0f;
    if (t < 64) pcnt[t] = 0.0f;
    if (t == 0) rowptr[N] = E;
}

// per bucket: count node degrees in LDS, local 128-scan -> rowptr/dinv, scatter csr
__global__ void k_place(const int* __restrict__ bcur, const int* __restrict__ buck,
                        const int* __restrict__ bbase, int* __restrict__ rowptr,
                        float* __restrict__ dinv, int* __restrict__ csr) {
    __shared__ int dc[128], sc[128], cur[128];
    int b = blockIdx.x, t = threadIdx.x;
    if (t < 128) dc[t] = 0;
    __syncthreads();
    int beg = b * CAP, end = bcur[b * BSTRIDE];
    for (int i = beg + t; i < end; i += 256) atomicAdd(&dc[buck[i] & 127], 1);
    __syncthreads();
    int v = (t < 128) ? dc[t] : 0;
    if (t < 128) sc[t] = v;
    __syncthreads();
    for (int o = 1; o < 128; o <<= 1) {
        int x = 0;
        if (t < 128 && t >= o) x = sc[t - o];
        __syncthreads();
        if (t < 128) sc[t] += x;
        __syncthreads();
    }
    if (t < 128) {
        int r = bbase[b] + sc[t] - v;   // exclusive
        rowptr[b * 128 + t] = r;
        cur[t] = r;
        dinv[b * 128 + t] = rsqrtf((float)(v + 1));  // +1 self loop
    }
    __syncthreads();
    for (int i = beg + t; i < end; i += 256) {
        int e = buck[i];
        int p = atomicAdd(&cur[e & 127], 1);
        csr[p] = e >> 7;
    }
}

// y[n][j] = fp16( dinv[n] * ( sum_f hnorm[n][f]*W[f][j] + brow[j] ) )
// BN fold in-block: Ws = rstd[f]*W, brow[j] = -sum_f mean[f]*Ws[f][j].
// block 256 threads, 64 rows/block; thread = 4x4 output tile.
template <int HIN>
__global__ void k_gemm(const void* __restrict__ hv, const float* __restrict__ W,
                       const float* __restrict__ mean, const float* __restrict__ rstd,
                       int has_stats, const float* __restrict__ dinv,
                       __half* __restrict__ y) {
    __shared__ float Ws[4096];        // [f][c] 64x64, scaled by rstd[f]
    __shared__ float hs[64 * 65];     // [row][f], stride 65
    __shared__ float sm[64], sr[64], bs[64];
    int t = threadIdx.x;
    int rowBase = blockIdx.x * 64;
    if (t < 64) {
        sm[t] = has_stats ? mean[t] : 0.0f;
        sr[t] = has_stats ? rstd[t] : 1.0f;
    }
    __syncthreads();
#pragma unroll
    for (int k = 0; k < 4; ++k) {
        int i = t + k * 256;              // float4 index; row f = i>>4
        float4 wv = ((const float4*)W)[i];
        float s = sr[i >> 4];
        wv.x *= s; wv.y *= s; wv.z *= s; wv.w *= s;
        ((float4*)Ws)[i] = wv;
    }
    if (HIN) {
        const uint4* src = (const uint4*)((const __half*)hv + (size_t)rowBase * 64);
#pragma unroll
        for (int k = 0; k < 2; ++k) {
            int i = t + k * 256;          // 0..511 uint4s; each = 8 halves
            int row = i >> 3, c8 = i & 7;
            uint4 u = src[i];
            const __half2* hp = (const __half2*)&u;
            float* dst = &hs[row * 65 + c8 * 8];
#pragma unroll
            for (int j = 0; j < 4; ++j) {
                dst[2 * j + 0] = __low2float(hp[j]);
                dst[2 * j + 1] = __high2float(hp[j]);
            }
        }
    } else {
        const float4* src = (const float4*)((const float*)hv + (size_t)rowBase * 64);
#pragma unroll
        for (int k = 0; k < 4; ++k) {
            int i = t + k * 256;
            int row = i >> 4, c4 = i & 15;
            float4 v = src[i];
            float* dst = &hs[row * 65 + c4 * 4];
            dst[0] = v.x; dst[1] = v.y; dst[2] = v.z; dst[3] = v.w;
        }
    }
    __syncthreads();
    if (t < 64) {
        float acc = 0.0f;
        for (int f = 0; f < 64; ++f) acc += sm[f] * Ws[f * 64 + t];
        bs[t] = -acc;
    }
    __syncthreads();
    int rg = t >> 4;   // 0..15
    int cg = t & 15;   // 0..15
    float4 a0, a1, a2, a3;
    {
        float bx = bs[cg * 4 + 0], by = bs[cg * 4 + 1];
        float bz = bs[cg * 4 + 2], bw = bs[cg * 4 + 3];
        a0 = {bx, by, bz, bw}; a1 = a0; a2 = a0; a3 = a0;
    }
    const float* h0 = &hs[(rg * 4 + 0) * 65];
    const float* h1 = &hs[(rg * 4 + 1) * 65];
    const float* h2 = &hs[(rg * 4 + 2) * 65];
    const float* h3 = &hs[(rg * 4 + 3) * 65];
#pragma unroll 4
    for (int f = 0; f < 64; ++f) {
        float4 wv = ((float4*)Ws)[f * 16 + cg];
        float v0 = h0[f], v1 = h1[f], v2 = h2[f], v3 = h3[f];
        a0.x += v0 * wv.x; a0.y += v0 * wv.y; a0.z += v0 * wv.z; a0.w += v0 * wv.w;
        a1.x += v1 * wv.x; a1.y += v1 * wv.y; a1.z += v1 * wv.z; a1.w += v1 * wv.w;
        a2.x += v2 * wv.x; a2.y += v2 * wv.y; a2.z += v2 * wv.z; a2.w += v2 * wv.w;
        a3.x += v3 * wv.x; a3.y += v3 * wv.y; a3.z += v3 * wv.z; a3.w += v3 * wv.w;
    }
    float d0 = dinv[rowBase + rg * 4 + 0];
    float d1 = dinv[rowBase + rg * 4 + 1];
    float d2 = dinv[rowBase + rg * 4 + 2];
    float d3 = dinv[rowBase + rg * 4 + 3];
    uint2* y2 = (uint2*)y;
    size_t ob = (size_t)(rowBase + rg * 4) * 16 + cg;
    y2[ob + 0]  = {pack2h(a0.x * d0, a0.y * d0), pack2h(a0.z * d0, a0.w * d0)};
    y2[ob + 16] = {pack2h(a1.x * d1, a1.y * d1), pack2h(a1.z * d1, a1.w * d1)};
    y2[ob + 32] = {pack2h(a2.x * d2, a2.y * d2), pack2h(a2.z * d2, a2.w * d2)};
    y2[ob + 48] = {pack2h(a3.x * d3, a3.y * d3), pack2h(a3.z * d3, a3.w * d3)};
}

// out[n] = relu?( dinv[n]*(y[n] + sum_{src} y[src]) + bias ), stored fp16.
// Block = 64 consecutive nodes; csr window staged in LDS (kills per-node global
// index chain). Octet (8 lanes) = 1 node; lane j = feats 8j..8j+7 (uint4 row).
// 4-deep unroll -> 32 independent row loads in flight per wave.
template <int RELU>
__global__ __launch_bounds__(512) void k_agg(
        const __half* __restrict__ y, const int* __restrict__ rowptr,
        const int* __restrict__ csr, const float* __restrict__ dinv,
        const float* __restrict__ bias, __half* __restrict__ hout,
        float* __restrict__ partials, int N) {
    __shared__ int lcsr[2048];
    __shared__ int lrp[65];
    __shared__ float SW[16][64];            // [0..7]=sum per wave, [8..15]=sumsq
    int t = threadIdx.x;
    int lane = t & 63, wid = t >> 6;        // 8 waves
    int o = lane >> 3, j = lane & 7;        // octet 0..7, lane-in-octet 0..7
    int nodeBase = blockIdx.x * 64;
    if (t < 65) lrp[t] = rowptr[nodeBase + t];
    __syncthreads();
    int wbase = lrp[0];
    int wlen = lrp[64] - wbase;
    bool fits = (wlen <= 2048);
    if (fits)
        for (int i = t; i < wlen; i += 512) lcsr[i] = csr[wbase + i];
    __syncthreads();

    int n = nodeBase + wid * 8 + o;
    int beg = lrp[wid * 8 + o] - wbase;
    int d = lrp[wid * 8 + o + 1] - wbase - beg;
    const uint4* y4 = (const uint4*)y;      // row = 8 uint4 = 128B
    float a[8] = {0, 0, 0, 0, 0, 0, 0, 0};

    if (fits) {
        const int* cp = lcsr + beg;
        int k = 0;
        for (; k + 4 <= d; k += 4) {
            int s0 = cp[k], s1 = cp[k + 1], s2 = cp[k + 2], s3 = cp[k + 3];
            uint4 u0 = y4[(size_t)s0 * 8 + j];
            uint4 u1 = y4[(size_t)s1 * 8 + j];
            uint4 u2 = y4[(size_t)s2 * 8 + j];
            uint4 u3 = y4[(size_t)s3 * 8 + j];
            acc8(a, u0); acc8(a, u1); acc8(a, u2); acc8(a, u3);
        }
        for (; k < d; ++k) {
            uint4 u0 = y4[(size_t)cp[k] * 8 + j];
            acc8(a, u0);
        }
    } else {                                 // ~never (window 32 sigma below cap)
        const int* cp = csr + wbase + beg;
        int k = 0;
        for (; k + 4 <= d; k += 4) {
            int s0 = cp[k], s1 = cp[k + 1], s2 = cp[k + 2], s3 = cp[k + 3];
            uint4 u0 = y4[(size_t)s0 * 8 + j];
            uint4 u1 = y4[(size_t)s1 * 8 + j];
            uint4 u2 = y4[(size_t)s2 * 8 + j];
            uint4 u3 = y4[(size_t)s3 * 8 + j];
            acc8(a, u0); acc8(a, u1); acc8(a, u2); acc8(a, u3);
        }
        for (; k < d; ++k) {
            uint4 u0 = y4[(size_t)cp[k] * 8 + j];
            acc8(a, u0);
        }
    }
    uint4 us = y4[(size_t)n * 8 + j];       // self term
    acc8(a, us);

    float dv = dinv[n];
    const float4* b4 = (const float4*)bias;
    float4 blo = b4[j * 2], bhi = b4[j * 2 + 1];
    float v[8];
    v[0] = a[0] * dv + blo.x; v[1] = a[1] * dv + blo.y;
    v[2] = a[2] * dv + blo.z; v[3] = a[3] * dv + blo.w;
    v[4] = a[4] * dv + bhi.x; v[5] = a[5] * dv + bhi.y;
    v[6] = a[6] * dv + bhi.z; v[7] = a[7] * dv + bhi.w;
    if (RELU) {
#pragma unroll
        for (int i = 0; i < 8; ++i) v[i] = fmaxf(v[i], 0.0f);
    }
    uint4 ov;
    ov.x = pack2h(v[0], v[1]); ov.y = pack2h(v[2], v[3]);
    ov.z = pack2h(v[4], v[5]); ov.w = pack2h(v[6], v[7]);
    ((uint4*)hout)[(size_t)n * 8 + j] = ov;

    // BN partials: per lane = its node's 8 feature values; combine octets (nodes)
    float q[8];
#pragma unroll
    for (int i = 0; i < 8; ++i) q[i] = v[i] * v[i];
#pragma unroll
    for (int st = 8; st <= 32; st <<= 1) {
#pragma unroll
        for (int i = 0; i < 8; ++i) {
            v[i] += __shfl_xor(v[i], st);
            q[i] += __shfl_xor(q[i], st);
        }
    }
    if (o == 0) {
#pragma unroll
        for (int i = 0; i < 8; ++i) {
            SW[wid][j * 8 + i] = v[i];
            SW[8 + wid][j * 8 + i] = q[i];
        }
    }
    __syncthreads();
    if (t < 64) {
        float s = 0.0f, qq = 0.0f;
#pragma unroll
        for (int w = 0; w < 8; ++w) {
            s += SW[w][t];
            qq += SW[8 + w][t];
        }
        partials[(size_t)blockIdx.x * 128 + t] = s;
        partials[(size_t)blockIdx.x * 128 + 64 + t] = qq;
    }
}

// one block per feature: reduce partials -> mean, rstd
__global__ void k_stats(const float* __restrict__ partials, int nblk,
                        float* __restrict__ mean, float* __restrict__ rstd, float invN) {
    __shared__ float sh[256];
    int f = blockIdx.x, t = threadIdx.x;
    float s = 0.0f, q = 0.0f;
    for (int b = t; b < nblk; b += 256) {
        s += partials[(size_t)b * 128 + f];
        q += partials[(size_t)b * 128 + 64 + f];
    }
    sh[t] = s;
    __syncthreads();
    for (int o = 128; o > 0; o >>= 1) {
        if (t < o) sh[t] += sh[t + o];
        __syncthreads();
    }
    float S = sh[0];
    __syncthreads();
    sh[t] = q;
    __syncthreads();
    for (int o = 128; o > 0; o >>= 1) {
        if (t < o) sh[t] += sh[t + o];
        __syncthreads();
    }
    if (t == 0) {
        float Qs = sh[0];
        float m = S * invN;
        float var = Qs * invN - m * m;
        mean[f] = m;
        rstd[f] = rsqrtf(var + 1e-5f);
    }
}

// mean pool with on-the-fly BN of final layer; batch is sorted -> per-run register accum
__global__ void k_pool(const __half* __restrict__ h, const int* __restrict__ batch,
                       const float* __restrict__ mean, const float* __restrict__ rstd,
                       float* __restrict__ psum, float* __restrict__ pcnt) {
    int lane = threadIdx.x;
    int base = blockIdx.x * 64;
    float m = mean[lane], r = rstd[lane];
    int cur = batch[base];
    float acc = 0.0f;
    int runlen = 0;
    for (int i = 0; i < 64; ++i) {
        int n = base + i;
        int g = batch[n];
        if (g != cur) {
            atomicAdd(&psum[cur * 64 + lane], acc);
            if (lane == 0) atomicAdd(&pcnt[cur], (float)runlen);
            acc = 0.0f;
            runlen = 0;
            cur = g;
        }
        acc += (__half2float(h[(size_t)n * 64 + lane]) - m) * r;
        runlen++;
    }
    atomicAdd(&psum[cur * 64 + lane], acc);
    if (lane == 0) atomicAdd(&pcnt[cur], (float)runlen);
}

// logits = pooled @ clfW^T + clfb ; softmax over 16 classes. 1 block x 1024 threads.
__global__ void k_head(const float* __restrict__ psum, const float* __restrict__ pcnt,
                       const float* __restrict__ clfW, const float* __restrict__ clfb,
                       float* __restrict__ out) {
    __shared__ float ps[64 * 64];
    __shared__ float wl[16 * 64];
    __shared__ float ci[64];
    int t = threadIdx.x;
    ((float4*)ps)[t] = ((const float4*)psum)[t];
    if (t < 256) ((float4*)wl)[t] = ((const float4*)clfW)[t];
    if (t < 64) ci[t] = 1.0f / fmaxf(pcnt[t], 1.0f);
    __syncthreads();
    int g = t >> 4, c = t & 15;
    float acc = 0.0f;
#pragma unroll 8
    for (int f = 0; f < 64; ++f) acc += ps[g * 64 + f] * wl[c * 64 + f];
    acc = acc * ci[g] + clfb[c];
    float mx = acc;
    for (int o = 1; o < 16; o <<= 1) mx = fmaxf(mx, __shfl_xor(mx, o, 16));
    float e = __expf(acc - mx);
    float s = e;
    for (int o = 1; o < 16; o <<= 1) s += __shfl_xor(s, o, 16);
    out[t] = e / s;
}

extern "C" void kernel_launch(void* const* d_in, const int* in_sizes, int n_in,
                              void* d_out, int out_size, void* d_ws, size_t ws_size,
                              hipStream_t stream) {
    const float* x    = (const float*)d_in[0];
    const int*   ei   = (const int*)d_in[1];
    const int*   bat  = (const int*)d_in[2];
    const float* W0   = (const float*)d_in[3];
    const float* b0   = (const float*)d_in[4];
    const float* W1   = (const float*)d_in[5];
    const float* b1   = (const float*)d_in[6];
    const float* W2   = (const float*)d_in[7];
    const float* b2   = (const float*)d_in[8];
    const float* clfW = (const float*)d_in[9];
    const float* clfb = (const float*)d_in[10];
    float* out = (float*)d_out;

    const int N = in_sizes[0] / 64;   // 65536
    const int E = in_sizes[1] / 2;    // 1048576
    const int AB = N / 64;            // 1024 agg blocks

    char* w = (char*)d_ws;
    size_t off = 0;
    auto take = [&](size_t bytes) -> void* {
        off = (off + 255) & ~(size_t)255;
        void* p = w + off;
        off += bytes;
        return p;
    };
    int*    rowptr   = (int*)take((size_t)(N + 1) * 4);
    int*    bcur     = (int*)take((size_t)NBKT * BSTRIDE * 4);
    int*    bbase    = (int*)take((size_t)NBKT * 4);
    float*  dinv     = (float*)take((size_t)N * 4);
    int*    csr      = (int*)take((size_t)E * 4);
    __half* y        = (__half*)take((size_t)N * 64 * 2);
    __half* hA       = (__half*)take((size_t)N * 64 * 2);
    __half* hB       = (__half*)take((size_t)N * 64 * 2);
    float*  partials = (float*)take((size_t)AB * 128 * 4);
    float*  mean     = (float*)take(256);
    float*  rstd     = (float*)take(256);
    float*  psum     = (float*)take(64 * 64 * 4);
    float*  pcnt     = (float*)take(64 * 4);
    // buck (NBKT*CAP ints = 8MB) overlaid on hB (8MB fp16): buck dead after k_place,
    // hB first written in layer-1 k_agg.
    int* buck = (int*)hB;

    k_binit<<<(NBKT + 255) / 256, 256, 0, stream>>>(bcur);
    k_bin<<<E / 4096, 256, 0, stream>>>(ei, E, bcur, buck);
    k_scanB<<<1, NBKT, 0, stream>>>(bcur, bbase, rowptr, psum, pcnt, N, E);
    k_place<<<NBKT, 256, 0, stream>>>(bcur, buck, bbase, rowptr, dinv, csr);

    const float invN = 1.0f / (float)N;

    // layer 0 (input x fp32, no BN on input)
    k_gemm<0><<<N / 64, 256, 0, stream>>>(x, W0, mean, rstd, 0, dinv, y);
    k_agg<1><<<AB, 512, 0, stream>>>(y, rowptr, csr, dinv, b0, hA, partials, N);
    k_stats<<<64, 256, 0, stream>>>(partials, AB, mean, rstd, invN);

    // layer 1
    k_gemm<1><<<N / 64, 256, 0, stream>>>(hA, W1, mean, rstd, 1, dinv, y);
    k_agg<1><<<AB, 512, 0, stream>>>(y, rowptr, csr, dinv, b1, hB, partials, N);
    k_stats<<<64, 256, 0, stream>>>(partials, AB, mean, rstd, invN);

    // layer 2 (no relu)
    k_gemm<1><<<N / 64, 256, 0, stream>>>(hB, W2, mean, rstd, 1, dinv, y);
    k_agg<0><<<AB, 512, 0, stream>>>(y, rowptr, csr, dinv, b2, hA, partials, N);
    k_stats<<<64, 256, 0, stream>>>(partials, AB, mean, rstd, invN);

    // pool (applies final BN on the fly) + head
    k_pool<<<N / 64, 64, 0, stream>>>(hA, bat, mean, rstd, psum, pcnt);
    k_head<<<1, 1024, 0, stream>>>(psum, pcnt, clfW, clfb, out);
}